// Round 10
// baseline (1302.418 us; speedup 1.0000x reference)
//
#include <hip/hip_runtime.h>
#include <hip/hip_bf16.h>
#include <hip/hip_fp16.h>

// 2-layer Elman RNN, S=64 B=64 H=E=512 V=10000.
// r10: recurrence split 4 ways by COLUMN so U is fully register-resident.
// Grid 32 blocks: group g = bid&7 (0..3 active), col-slice q = bid>>3.
// Group g's 4 blocks = {g, g+8, g+16, g+24} -> same XCD under the bid%8
// round-robin heuristic (perf-only assumption; protocol is placement-safe).
// Each wave owns 16 cols with U frags in 64 VGPRs (never spills at the
// 128-reg cap, unlike the 192-reg designs of r2-r8). Per-step h exchange:
// 8B-packed f16 via L2 'hx' + r1-proven fence/flag protocol.

typedef _Float16 f16;
typedef _Float16 f16x8 __attribute__((ext_vector_type(8)));
typedef float fvec4 __attribute__((ext_vector_type(4)));
typedef float f32x4 __attribute__((ext_vector_type(4)));
typedef unsigned int u32;
typedef u32 u32x2 __attribute__((ext_vector_type(2)));

#define AGENT __HIP_MEMORY_SCOPE_AGENT

__device__ __forceinline__ f32x4 mfma16(f16x8 a, f16x8 b, f32x4 c) {
    return __builtin_amdgcn_mfma_f32_16x16x32_f16(a, b, c, 0, 0, 0);
}

__device__ __forceinline__ f16x8 cvt_f16x8(fvec4 a, fvec4 b) {
    f16x8 r;
    r[0] = (f16)a[0]; r[1] = (f16)a[1]; r[2] = (f16)a[2]; r[3] = (f16)a[3];
    r[4] = (f16)b[0]; r[5] = (f16)b[1]; r[6] = (f16)b[2]; r[7] = (f16)b[3];
    return r;
}

// ---- fp32 -> f16 convert, 8 elems/thread ----
__global__ void cvt_f32_f16(const float* __restrict__ src, f16* __restrict__ dst, int n8) {
    int i = blockIdx.x * 256 + threadIdx.x;
    if (i >= n8) return;
    const fvec4* p = (const fvec4*)(src + (size_t)i * 8);
    *(f16x8*)(dst + (size_t)i * 8) = cvt_f16x8(p[0], p[1]);
}

// ---- Wd (10000x512) -> f16 padded to 10112 rows (zero pad) ----
__global__ void cvt_wd(const float* __restrict__ src, f16* __restrict__ dst) {
    int i = blockIdx.x * 256 + threadIdx.x;
    if (i >= 647168) return;
    if (i < 640000) {
        const fvec4* p = (const fvec4*)(src + (size_t)i * 8);
        *(f16x8*)(dst + (size_t)i * 8) = cvt_f16x8(p[0], p[1]);
    } else {
        f16x8 z = {};
        *(f16x8*)(dst + (size_t)i * 8) = z;
    }
}

// ---- gather X = f16(emb[tokens]) : (4096, 512) ----
__global__ void gather_x(const int* __restrict__ toks, const float* __restrict__ emb,
                         f16* __restrict__ xb) {
    int i = blockIdx.x * 256 + threadIdx.x;
    if (i >= 262144) return;
    int row = i >> 6, seg = i & 63;
    int tok = toks[row];
    const fvec4* p = (const fvec4*)(emb + (size_t)tok * 512 + seg * 8);
    *(f16x8*)(xb + (size_t)row * 512 + seg * 8) = cvt_f16x8(p[0], p[1]);
}

__global__ void zero_u32(u32* p, int n) {
    int i = blockIdx.x * 256 + threadIdx.x;
    if (i < n) p[i] = 0;
}

// ---- GEMM (round-3 proven): C = A(M,512)f16 @ Bm(Npad,512)f16^T + biases ----
// MODE 0: C row-major (M,N).  MODE 1: permuted fragment layout:
// idx = (((t*4+m)*8+wp)*64 + lanep)*16 + n*4 + rp.
template <int MODE>
__global__ __launch_bounds__(256) void gemm_bt(
    const f16* __restrict__ A, const f16* __restrict__ Bm,
    const float* __restrict__ bias1, const float* __restrict__ bias2,
    float* __restrict__ C, int N)
{
    const int tM = blockIdx.x * 128;
    const int tN = blockIdx.y * 128;
    const int tid = threadIdx.x;
    const int l = tid & 63, w = tid >> 6;
    const int wr = w >> 1, wc = w & 1;
    const int l15 = l & 15, l4 = l >> 4;

    __shared__ f16 As[128 * 40];
    __shared__ f16 Bs[128 * 40];

    f32x4 acc[4][4] = {};

    for (int ks = 0; ks < 16; ++ks) {
        const int k0 = ks * 32;
        __syncthreads();
#pragma unroll
        for (int it = 0; it < 2; ++it) {
            int c = tid + it * 256;
            int row = c >> 2, seg = c & 3;
            *(f16x8*)(&As[row * 40 + seg * 8]) =
                *(const f16x8*)(A + (size_t)(tM + row) * 512 + k0 + seg * 8);
            *(f16x8*)(&Bs[row * 40 + seg * 8]) =
                *(const f16x8*)(Bm + (size_t)(tN + row) * 512 + k0 + seg * 8);
        }
        __syncthreads();
        f16x8 af[4], bf[4];
#pragma unroll
        for (int m = 0; m < 4; ++m)
            af[m] = *(const f16x8*)(&As[(wr * 64 + m * 16 + l15) * 40 + 8 * l4]);
#pragma unroll
        for (int n = 0; n < 4; ++n)
            bf[n] = *(const f16x8*)(&Bs[(wc * 64 + n * 16 + l15) * 40 + 8 * l4]);
#pragma unroll
        for (int m = 0; m < 4; ++m)
#pragma unroll
            for (int n = 0; n < 4; ++n)
                acc[m][n] = mfma16(af[m], bf[n], acc[m][n]);
    }

    if (MODE == 0) {
#pragma unroll
        for (int n = 0; n < 4; ++n) {
            int col = tN + wc * 64 + n * 16 + l15;
            if (col >= N) continue;
            float bsum = (bias1 ? bias1[col] : 0.f) + (bias2 ? bias2[col] : 0.f);
#pragma unroll
            for (int m = 0; m < 4; ++m)
#pragma unroll
                for (int r = 0; r < 4; ++r) {
                    int row = tM + wr * 64 + m * 16 + l4 * 4 + r;
                    C[(size_t)row * N + col] = acc[m][n][r] + bsum;
                }
        }
    } else {
        const int t  = blockIdx.x * 2 + wr;
        const int wp = blockIdx.y * 2 + wc;
        const int lp_hi = (l15 >> 2) * 16;
        const int rp = l15 & 3;
#pragma unroll
        for (int n = 0; n < 4; ++n) {
            int col = tN + wc * 64 + n * 16 + l15;
            float bsum = bias1[col] + bias2[col];
#pragma unroll
            for (int m = 0; m < 4; ++m) {
#pragma unroll
                for (int r = 0; r < 4; ++r) {
                    int lanep = lp_hi + l4 * 4 + r;
                    size_t idx = ((((size_t)t * 4 + m) * 8 + wp) * 64 + lanep) * 16
                                 + n * 4 + rp;
                    C[idx] = acc[m][n][r] + bsum;
                }
            }
        }
    }
}

// ---- Recurrence, column-split 4 ways: h_t = tanh(ain_t + U @ h_{t-1}^T) ----
// Block (g,q): 16 batch rows (group g), cols [q*128, q*128+128). 8 waves,
// wave wv owns 16 cols; U frags wf[16] = 64 VGPRs, fully resident.
// h exchanged per step via hx (f16, [g][t&1][16][512]) + flags.
__global__ __launch_bounds__(512) void recur_split(
    const float* __restrict__ Ainp,  // permuted preactivation (from gemm_bt<1>)
    const float* __restrict__ U,     // (512,512) fp32 row-major U[c][k]
    const float* __restrict__ h0,    // (64,512) initial hidden
    f16* __restrict__ Hh,            // (4096,512) f16 history out (row-major)
    float* __restrict__ outTail,     // (64,512) fp32 final hidden out
    f16* __restrict__ hx,            // (4,2,16,512) f16 exchange buffer
    u32* __restrict__ flags)         // (4,4) step flags, pre-zeroed
{
    const int bid = blockIdx.x;
    const int g = bid & 7;
    if (g >= 4) return;                  // 16 of 32 blocks active
    const int q = bid >> 3;              // col-slice 0..3
    const int tid = threadIdx.x;
    const int l = tid & 63, wv = tid >> 6;
    const int l15 = l & 15, l4 = l >> 4;
    const int cs = q * 128 + wv * 16;    // wave's column base

    __shared__ __align__(16) char smem[32768];   // 2 x 16KB h staging dbuf

    // ---- one-time: U frags resident (wf[kk] = U[cs+l15][kk*32+8*l4 ..+7]) ----
    f16x8 wf[16];
    {
        const float* urow = U + (size_t)(cs + l15) * 512 + 8 * l4;
#pragma unroll
        for (int kk = 0; kk < 16; ++kk) {
            const fvec4* p = (const fvec4*)(urow + kk * 32);
            wf[kk] = cvt_f16x8(p[0], p[1]);
        }
    }

    u32* flg = flags + g * 4;
    f16* hxg = hx + (size_t)g * 16384;   // [2][16][512] f16
    const int sw = (l15 & 7) << 4;

    for (int t = 0; t < 64; ++t) {
        // ---- wait for all 4 slices of h(t-1) ----
        if (t > 0) {
            if (tid == 0) {
#pragma unroll
                for (int qq = 0; qq < 4; ++qq)
                    while (__hip_atomic_load(&flg[qq], __ATOMIC_ACQUIRE, AGENT) <
                           (u32)t)
                        __builtin_amdgcn_s_sleep(1);
            }
            __syncthreads();
        }
        // ---- stage h(t-1) (16x512) -> swizzled LDS ----
        char* hb = smem + (t & 1) * 16384;
        if (t == 0) {
            for (int c = tid; c < 1024; c += 512) {
                int row = c >> 6, seg = c & 63;
                const fvec4* p =
                    (const fvec4*)(h0 + (size_t)(g * 16 + row) * 512 + seg * 8);
                *(f16x8*)(hb + row * 1024 + ((seg * 16) ^ ((row & 7) << 4))) =
                    cvt_f16x8(p[0], p[1]);
            }
        } else {
            const f16* hsrc = hxg + ((t - 1) & 1) * 8192;
            for (int c = tid; c < 1024; c += 512) {
                int row = c >> 6, seg = c & 63;
                *(f16x8*)(hb + row * 1024 + ((seg * 16) ^ ((row & 7) << 4))) =
                    *(const f16x8*)(hsrc + row * 512 + seg * 8);
            }
        }
        __syncthreads();

        // ---- ain: one f32x4/lane from the gemm_bt<1> permuted layout ----
        // consumer map: wp = q*2+(wv>>2), n = wv&3, lanep = l  (verified)
        const float* ab = Ainp +
            (((size_t)t * 4 + g) * 8 + q * 2 + (wv >> 2)) * 1024 + l * 16 +
            (wv & 3) * 4;
        f32x4 acc = *(const f32x4*)ab;

        const char* hrd = hb + l15 * 1024;
#pragma unroll
        for (int kk = 0; kk < 16; ++kk) {
            f16x8 h = *(const f16x8*)(hrd + ((kk * 64 + l4 * 16) ^ sw));
            acc = mfma16(wf[kk], h, acc);
        }

        // ---- tanh + pack + export (lane: row l15, cols cs+l4*4 .. +3) ----
        f32x4 v;
#pragma unroll
        for (int r = 0; r < 4; ++r) {
            float e = __expf(2.0f * acc[r]);
            v[r] = 1.0f - 2.0f * __builtin_amdgcn_rcpf(e + 1.0f);
        }
        f16 c0f = (f16)v[0], c1f = (f16)v[1], c2f = (f16)v[2], c3f = (f16)v[3];
        u32 p0 = ((u32)__builtin_bit_cast(unsigned short, c1f) << 16) |
                 (u32)__builtin_bit_cast(unsigned short, c0f);
        u32 p1 = ((u32)__builtin_bit_cast(unsigned short, c3f) << 16) |
                 (u32)__builtin_bit_cast(unsigned short, c2f);
        u32x2 pk; pk[0] = p0; pk[1] = p1;
        const int c0 = cs + l4 * 4;
        *(u32x2*)(hxg + (t & 1) * 8192 + l15 * 512 + c0) = pk;   // exchange
        *(u32x2*)(Hh + ((size_t)t * 64 + g * 16 + l15) * 512 + c0) = pk;
        if (t == 63)
            *(f32x4*)(outTail + (size_t)(g * 16 + l15) * 512 + c0) = v;

        __threadfence();
        __syncthreads();
        if (tid == 0)
            __hip_atomic_store(&flg[q], (u32)(t + 1), __ATOMIC_RELEASE, AGENT);
    }
}

extern "C" void kernel_launch(void* const* d_in, const int* in_sizes, int n_in,
                              void* d_out, int out_size, void* d_ws, size_t ws_size,
                              hipStream_t stream) {
    const int*   toks   = (const int*)d_in[0];
    const float* hidden = (const float*)d_in[1];
    const float* emb    = (const float*)d_in[2];
    const float* W0  = (const float*)d_in[3];
    const float* bW0 = (const float*)d_in[4];
    const float* W1  = (const float*)d_in[5];
    const float* bW1 = (const float*)d_in[6];
    const float* U0  = (const float*)d_in[7];
    const float* bU0 = (const float*)d_in[8];
    const float* U1  = (const float*)d_in[9];
    const float* bU1 = (const float*)d_in[10];
    const float* Wd  = (const float*)d_in[11];
    const float* bd  = (const float*)d_in[12];
    float* out = (float*)d_out;

    char* ws = (char*)d_ws;
    f16*   W0h  = (f16*)(ws + 0);               // 524288
    f16*   W1h  = (f16*)(ws + 524288);          // 524288
    f16*   Wdh  = (f16*)(ws + 1048576);         // 10354688
    f16*   Xb   = (f16*)(ws + 11403264);        // 4194304
    f16*   H0h  = (f16*)(ws + 15597568);        // 4194304
    f16*   H1h  = (f16*)(ws + 19791872);        // 4194304
    float* A0   = (float*)(ws + 23986176);      // 8388608 (permuted)
    float* B1   = (float*)(ws + 32374784);      // 8388608 (permuted)
    f16*   hx   = (f16*)(ws + 40763392);        // 131072 (shared by both layers)
    u32*   flags= (u32*)(ws + 40894464);        // 128 B (2 layers x 16)

    cvt_f32_f16<<<128, 256, 0, stream>>>(W0, W0h, 32768);
    cvt_f32_f16<<<128, 256, 0, stream>>>(W1, W1h, 32768);
    cvt_wd<<<2528, 256, 0, stream>>>(Wd, Wdh);
    gather_x<<<1024, 256, 0, stream>>>(toks, emb, Xb);
    zero_u32<<<1, 256, 0, stream>>>(flags, 32);

    // A0 = perm(X @ W0^T + bW0 + bU0)
    gemm_bt<1><<<dim3(32, 4), 256, 0, stream>>>(Xb, W0h, bW0, bU0, A0, 512);
    // layer 0 recurrence (16 active blocks, col-split, reg-resident U)
    recur_split<<<32, 512, 0, stream>>>(A0, U0, hidden, H0h,
                                        out + 40960000, hx, flags);
    // B1 = perm(H0 @ W1^T + bW1 + bU1)
    gemm_bt<1><<<dim3(32, 4), 256, 0, stream>>>(H0h, W1h, bW1, bU1, B1, 512);
    // layer 1 recurrence
    recur_split<<<32, 512, 0, stream>>>(B1, U1, hidden + 32768, H1h,
                                        out + 40960000 + 32768, hx, flags + 16);
    // logits = H1 @ Wd^T + bd
    gemm_bt<0><<<dim3(32, 79), 256, 0, stream>>>(H1h, Wdh, bd, nullptr, out, 10000);
}